// Round 1
// baseline (62.449 us; speedup 1.0000x reference)
//
#include <hip/hip_runtime.h>

#define NEG_FILL -10000000000.0f

// spans: [B=2048][L=13][S=4][D=1024] f32
// mask : [B=2048][S=4] i32
// out  : [B=2048][L=13][D=1024] f32  = max over S of (mask ? spans : NEG_FILL)
//
// One block per (b,l); 256 threads; each thread owns one float4 of D.
// Mask test is uniform per (b,s) -> wave-uniform branch skips the whole
// coalesced load when masked (saves ~50% of read traffic for random mask).
__global__ __launch_bounds__(256) void MaxSpanRepr_kernel(
    const float4* __restrict__ spans,
    const int* __restrict__ mask,
    float4* __restrict__ out) {
    const int D4 = 1024 / 4;  // 256 float4 per row
    int bl = blockIdx.x;      // b*13 + l
    int b  = bl / 13;
    int d4 = threadIdx.x;     // 0..255

    // mask row for this batch (4 ints, 16B-aligned)
    int m0 = mask[b * 4 + 0];
    int m1 = mask[b * 4 + 1];
    int m2 = mask[b * 4 + 2];
    int m3 = mask[b * 4 + 3];

    const float4* base = spans + (size_t)bl * 4 * D4 + d4;

    float4 acc = make_float4(NEG_FILL, NEG_FILL, NEG_FILL, NEG_FILL);
    if (m0 != 0) {
        float4 v = base[0 * D4];
        acc.x = fmaxf(acc.x, v.x); acc.y = fmaxf(acc.y, v.y);
        acc.z = fmaxf(acc.z, v.z); acc.w = fmaxf(acc.w, v.w);
    }
    if (m1 != 0) {
        float4 v = base[1 * D4];
        acc.x = fmaxf(acc.x, v.x); acc.y = fmaxf(acc.y, v.y);
        acc.z = fmaxf(acc.z, v.z); acc.w = fmaxf(acc.w, v.w);
    }
    if (m2 != 0) {
        float4 v = base[2 * D4];
        acc.x = fmaxf(acc.x, v.x); acc.y = fmaxf(acc.y, v.y);
        acc.z = fmaxf(acc.z, v.z); acc.w = fmaxf(acc.w, v.w);
    }
    if (m3 != 0) {
        float4 v = base[3 * D4];
        acc.x = fmaxf(acc.x, v.x); acc.y = fmaxf(acc.y, v.y);
        acc.z = fmaxf(acc.z, v.z); acc.w = fmaxf(acc.w, v.w);
    }

    out[(size_t)bl * D4 + d4] = acc;
}

extern "C" void kernel_launch(void* const* d_in, const int* in_sizes, int n_in,
                              void* d_out, int out_size, void* d_ws, size_t ws_size,
                              hipStream_t stream) {
    const float4* spans = (const float4*)d_in[0];
    const int* mask = (const int*)d_in[1];
    float4* out = (float4*)d_out;

    const int B = 2048, L = 13;
    dim3 grid(B * L);   // 26624 blocks
    dim3 block(256);
    MaxSpanRepr_kernel<<<grid, block, 0, stream>>>(spans, mask, out);
}

// Round 2
// 59.407 us; speedup vs baseline: 1.0512x; 1.0512x over previous
//
#include <hip/hip_runtime.h>

#define NEG_FILL -10000000000.0f

typedef float f32x4 __attribute__((ext_vector_type(4)));

__device__ __forceinline__ f32x4 max4(f32x4 a, f32x4 b) {
    f32x4 r;
    r.x = fmaxf(a.x, b.x);
    r.y = fmaxf(a.y, b.y);
    r.z = fmaxf(a.z, b.z);
    r.w = fmaxf(a.w, b.w);
    return r;
}

// spans: [B=2048][L=13][S=4][D=1024] f32
// mask : [B=2048][S=4] i32
// out  : [B=2048][L=13][D=1024] f32 = max over S of (mask ? spans : NEG_FILL)
//
// One block per (b,l), 128 threads, each thread owns TWO float4s of D.
// All conditional loads are hoisted into value-only branches (no consumer
// inside the branch) so up to 8 loads stay in flight per thread before the
// single vmcnt wait at the max-reduction.
__global__ __launch_bounds__(128) void MaxSpanRepr_kernel(
    const f32x4* __restrict__ spans,
    const int4* __restrict__ mask,
    f32x4* __restrict__ out) {
    const int D4 = 1024 / 4;  // 256 float4 per row
    int bl = blockIdx.x;      // b*13 + l
    int b  = bl / 13;         // compiler strength-reduces to magic-mul
    int t  = threadIdx.x;     // 0..127
    int i0 = t;
    int i1 = t + 128;

    int4 mv = mask[b];  // 16B-aligned uniform load (s_load_dwordx4)

    const f32x4* base = spans + (size_t)bl * 4 * D4;

    const f32x4 nf = {NEG_FILL, NEG_FILL, NEG_FILL, NEG_FILL};
    f32x4 a0 = nf, a1 = nf, a2 = nf, a3 = nf;
    f32x4 b0 = nf, b1 = nf, b2 = nf, b3 = nf;

    if (mv.x != 0) {
        a0 = __builtin_nontemporal_load(base + 0 * D4 + i0);
        b0 = __builtin_nontemporal_load(base + 0 * D4 + i1);
    }
    if (mv.y != 0) {
        a1 = __builtin_nontemporal_load(base + 1 * D4 + i0);
        b1 = __builtin_nontemporal_load(base + 1 * D4 + i1);
    }
    if (mv.z != 0) {
        a2 = __builtin_nontemporal_load(base + 2 * D4 + i0);
        b2 = __builtin_nontemporal_load(base + 2 * D4 + i1);
    }
    if (mv.w != 0) {
        a3 = __builtin_nontemporal_load(base + 3 * D4 + i0);
        b3 = __builtin_nontemporal_load(base + 3 * D4 + i1);
    }

    f32x4 r0 = max4(max4(a0, a1), max4(a2, a3));
    f32x4 r1 = max4(max4(b0, b1), max4(b2, b3));

    f32x4* o = out + (size_t)bl * D4;
    __builtin_nontemporal_store(r0, o + i0);
    __builtin_nontemporal_store(r1, o + i1);
}

extern "C" void kernel_launch(void* const* d_in, const int* in_sizes, int n_in,
                              void* d_out, int out_size, void* d_ws, size_t ws_size,
                              hipStream_t stream) {
    const f32x4* spans = (const f32x4*)d_in[0];
    const int4* mask = (const int4*)d_in[1];
    f32x4* out = (f32x4*)d_out;

    const int B = 2048, L = 13;
    dim3 grid(B * L);   // 26624 blocks
    dim3 block(128);
    MaxSpanRepr_kernel<<<grid, block, 0, stream>>>(spans, mask, out);
}